// Round 8
// baseline (308.044 us; speedup 1.0000x reference)
//
#include <hip/hip_runtime.h>

typedef __attribute__((ext_vector_type(8))) short bf16x8;
typedef __attribute__((ext_vector_type(4))) float floatx4;
typedef __attribute__((ext_vector_type(16))) float floatx16;

constexpr int BATCH = 4;
constexpr int SEQ   = 2048;
constexpr int DIMN  = 1024;
constexpr int M1    = BATCH * SEQ; // 8192

constexpr int G_ABY  = 16384;
constexpr int G_BUFB = G_ABY + 32768;   // 48KB per buffer
constexpr int G_LDSZ = 3 * G_BUFB;      // 147456

__device__ __forceinline__ short f2bf(float f) {
    union { float f; unsigned u; } x; x.f = f;
    unsigned r = x.u + 0x7fffu + ((x.u >> 16) & 1u); // RNE
    return (short)(r >> 16);
}
__device__ __forceinline__ float bf2f(short s) {
    union { unsigned u; float f; } x; x.u = ((unsigned)(unsigned short)s) << 16;
    return x.f;
}

__device__ __forceinline__ void async16(const void* g, void* l) {
    __builtin_amdgcn_global_load_lds(
        (const __attribute__((address_space(1))) unsigned int*)g,
        (__attribute__((address_space(3))) unsigned int*)l, 16, 0, 0);
}

#define WAITVM(N) asm volatile("s_waitcnt vmcnt(" #N ")" ::: "memory")
#define MEMFENCE  asm volatile("" ::: "memory")
#define BAR()     __builtin_amdgcn_s_barrier()
#define PRIO(x)   __builtin_amdgcn_s_setprio(x)

// ===========================================================================
// gemm128: 128x256 tile, BK=64, 8 waves (2M x 4N), per-wave 64x64.
// Schedule/staging/swizzle byte-identical to the verified round-4/6 core
// (triple buffer, stage t+2 during t, counted WAITVM(6) at P1-end).
// Inner compute: v_mfma_f32_32x32x16_bf16, per wave 2x2 C-tiles of 32x32.
//   A frag: row = lane&31, k = (lane>>5)*8 .. +7 (32x32 analog of the
//   session-verified 16x16 mapping);
//   C/D:    col = lane&31, row = (r&3) + 8*(r>>2) + 4*(lane>>5) [m74/m101].
// LDS buffer is passed in (hoisted to kernel scope) so multiple template
// instantiations in one kernel share a single 144KB allocation.
// BMODE: 0 = no bias, 1 = column bias (q/k proj), 2 = row bias (V^T proj).
// ===========================================================================
template<bool OUT_BF16, int BMODE>
__device__ __forceinline__ void gemm128(
    char* __restrict__ lds,
    const short* __restrict__ Ab, int lda,
    const short* __restrict__ Bb, int ldb,
    void* __restrict__ Cb, int ldc,
    const float* __restrict__ bias, int K, float scale,
    int m0, int n0)
{
    constexpr int ABY  = G_ABY;
    constexpr int BUFB = G_BUFB;

    const int t    = threadIdx.x;
    const int lane = t & 63;
    const int wave = t >> 6;
    const int wr   = wave >> 2;
    const int wc   = wave & 3;

    // ---- staging (identical to verified core) ----
    const int srow  = t >> 3;
    const int scol  = (((t & 7) * 16) ^ ((srow & 7) << 4)) >> 1;
    const short* pa0 = Ab + (size_t)(m0 + srow) * lda + scol;
    const short* pb0 = Bb + (size_t)(n0 + srow) * ldb + scol;
    const size_t rsa = (size_t)64 * lda;
    const size_t rsb = (size_t)64 * ldb;
    const int ldst = t * 16;

    // ---- 32x32 fragment read addressing ----
    const int l31   = lane & 31;
    const int swz   = (lane & 7) << 4;
    const int khalf = (lane >> 5) << 4;
    int colp[4];
    #pragma unroll
    for (int ks = 0; ks < 4; ++ks) colp[ks] = (ks * 32 + khalf) ^ swz;
    const int roA = (wr * 64 + l31) * 128;          // + mi*4096 + colp[ks]
    const int roB = ABY + (wc * 64 + l31) * 128;    // + ni*4096 + colp[ks]

    floatx16 acc[2][2];
    #pragma unroll
    for (int mi = 0; mi < 2; ++mi)
        #pragma unroll
        for (int ni = 0; ni < 2; ++ni)
            #pragma unroll
            for (int r = 0; r < 16; ++r) acc[mi][ni][r] = 0.f;

    auto stA = [&](int d, int kt) { const short* p = pa0 + kt * 64;
        async16(p,       lds + d +        ldst);
        async16(p + rsa, lds + d + 8192 + ldst); };
    auto stB01 = [&](int d, int kt) { const short* p = pb0 + kt * 64;
        async16(p,       lds + d + ABY +        ldst);
        async16(p + rsb, lds + d + ABY + 8192 + ldst); };
    auto stB23 = [&](int d, int kt) { const short* p = pb0 + kt * 64;
        async16(p + 2 * rsb, lds + d + ABY + 16384 + ldst);
        async16(p + 3 * rsb, lds + d + ABY + 24576 + ldst); };

    const int NT = K >> 6;

    stA(0, 0); stB01(0, 0); stB23(0, 0);
    if (NT > 1) { stA(BUFB, 1); stB01(BUFB, 1); stB23(BUFB, 1); WAITVM(6); }
    else        { WAITVM(0); }
    BAR(); MEMFENCE;

    int cb = 0;
    for (int tt = 0; tt < NT; ++tt) {
        const char* rb = lds + cb;
        int sb = cb + 2 * BUFB; if (sb >= 3 * BUFB) sb -= 3 * BUFB;
        bf16x8 a[2][2], b[2][2];

        // ---- P0 (ksteps 0,1); stage A + B01 of t+2
        #pragma unroll
        for (int mi = 0; mi < 2; ++mi)
            #pragma unroll
            for (int ks = 0; ks < 2; ++ks)
                a[mi][ks] = *(const bf16x8*)(rb + roA + mi * 4096 + colp[ks]);
        #pragma unroll
        for (int ni = 0; ni < 2; ++ni)
            #pragma unroll
            for (int ks = 0; ks < 2; ++ks)
                b[ni][ks] = *(const bf16x8*)(rb + roB + ni * 4096 + colp[ks]);
        if (tt + 2 < NT) { stA(sb, tt + 2); stB01(sb, tt + 2); }
        BAR(); MEMFENCE;
        PRIO(1);
        #pragma unroll
        for (int ks = 0; ks < 2; ++ks)
            #pragma unroll
            for (int mi = 0; mi < 2; ++mi)
                #pragma unroll
                for (int ni = 0; ni < 2; ++ni)
                    acc[mi][ni] = __builtin_amdgcn_mfma_f32_32x32x16_bf16(
                        a[mi][ks], b[ni][ks], acc[mi][ni], 0, 0, 0);
        PRIO(0); MEMFENCE;
        BAR(); MEMFENCE;

        // ---- P1 (ksteps 2,3); stage B23 of t+2; certify tile t+1
        #pragma unroll
        for (int mi = 0; mi < 2; ++mi)
            #pragma unroll
            for (int ks = 0; ks < 2; ++ks)
                a[mi][ks] = *(const bf16x8*)(rb + roA + mi * 4096 + colp[ks + 2]);
        #pragma unroll
        for (int ni = 0; ni < 2; ++ni)
            #pragma unroll
            for (int ks = 0; ks < 2; ++ks)
                b[ni][ks] = *(const bf16x8*)(rb + roB + ni * 4096 + colp[ks + 2]);
        if (tt + 2 < NT) stB23(sb, tt + 2);
        BAR(); MEMFENCE;
        PRIO(1);
        #pragma unroll
        for (int ks = 0; ks < 2; ++ks)
            #pragma unroll
            for (int mi = 0; mi < 2; ++mi)
                #pragma unroll
                for (int ni = 0; ni < 2; ++ni)
                    acc[mi][ni] = __builtin_amdgcn_mfma_f32_32x32x16_bf16(
                        a[mi][ks], b[ni][ks], acc[mi][ni], 0, 0, 0);
        PRIO(0); MEMFENCE;
        if (tt + 1 < NT) {
            if (tt + 2 < NT) { WAITVM(6); } else { WAITVM(0); }
        }
        BAR(); MEMFENCE;
        cb += BUFB; if (cb >= 3 * BUFB) cb = 0;
    }

    // ---- epilogue: C/D col = lane&31, row = (r&3) + 8*(r>>2) + 4*(lane>>5)
    const int rhi = (lane >> 5) * 4;
    #pragma unroll
    for (int mi = 0; mi < 2; ++mi) {
        #pragma unroll
        for (int ni = 0; ni < 2; ++ni) {
            const int gm0 = m0 + wr * 64 + mi * 32;
            const int gn  = n0 + wc * 64 + ni * 32 + l31;
            float cbv = 0.f;
            if (BMODE == 1) cbv = bias[gn];
            #pragma unroll
            for (int r = 0; r < 16; ++r) {
                const int row = (r & 3) + 8 * (r >> 2) + rhi;
                const int gm  = gm0 + row;
                float v = acc[mi][ni][r] * scale;
                if (BMODE == 1) v += cbv;
                if (BMODE == 2) v += bias[gm];
                if (OUT_BF16) ((short*)Cb)[(size_t)gm * ldc + gn] = f2bf(v);
                else          ((float*)Cb)[(size_t)gm * ldc + gn] = v;
            }
        }
    }
}

// ---------------------------------------------------------------------------
// proj: 768 blocks.
//   i<64:  q/k GEMM (2 mats x 32 tiles/xcd): O = X @ W^T + colbias
//   i>=64: V^T GEMM (32 blocks/xcd): v_t = Wv @ xv^T + rowbias  (m-tile=xcd)
// Eliminates the separate transpose_v pass. Single shared LDS block for
// both template instantiations (hoisted to kernel scope).
// ---------------------------------------------------------------------------
__global__ __launch_bounds__(512, 2)
void proj_qkv(const short* __restrict__ xq, const short* __restrict__ xk,
              const short* __restrict__ xv,
              const short* __restrict__ Wq_, const short* __restrict__ Wk_,
              const short* __restrict__ Wv_,
              const float* __restrict__ bq_, const float* __restrict__ bk_,
              const float* __restrict__ bv_,
              short* __restrict__ q, short* __restrict__ k, short* __restrict__ vt)
{
    __shared__ alignas(16) char smem[G_LDSZ];
    const int b   = blockIdx.x;
    const int xcd = b & 7;
    const int i   = b >> 3;          // 0..95
    if (i < 64) {
        const int z   = i >> 5;      // 0..1 (q,k)
        const int r   = i & 31;
        const int mm  = r >> 2;      // 0..7
        const int nn  = r & 3;       // 0..3
        const short* X = (z == 0) ? xq : xk;
        const short* W = (z == 0) ? Wq_ : Wk_;
        const float* bb = (z == 0) ? bq_ : bk_;
        short* O = (z == 0) ? q : k;
        gemm128<true, 1>(smem, X, DIMN, W, DIMN, (void*)O, DIMN, bb, DIMN, 1.f,
                         (xcd * 8 + mm) * 128, nn * 256);
    } else {
        const int r  = i - 64;       // 0..31
        const int bz = r >> 3;       // 0..3
        const int nn = r & 7;        // 0..7
        gemm128<true, 2>(smem, Wv_, DIMN,
                         xv + (size_t)bz * SEQ * DIMN, DIMN,
                         (void*)(vt + (size_t)bz * DIMN * SEQ), SEQ,
                         bv_, DIMN, 1.f,
                         xcd * 128, nn * 256);
    }
}

// scores: 512 blocks = 4 batch x 16 m-tiles(128) x 8 n-tiles(256).
__global__ __launch_bounds__(512, 2)
void gemm_scores(const short* __restrict__ q, const short* __restrict__ k,
                 short* __restrict__ S, float scale)
{
    __shared__ alignas(16) char smem[G_LDSZ];
    const int b   = blockIdx.x;
    const int xcd = b & 7;
    const int i   = b >> 3;          // 0..63
    const int bz  = xcd >> 1;
    const int mh  = xcd & 1;
    const int mm  = i >> 3;          // 0..7
    const int nn  = i & 7;           // 0..7
    gemm128<true, 0>(smem, q + (size_t)bz * SEQ * DIMN, DIMN,
                     k + (size_t)bz * SEQ * DIMN, DIMN,
                     (void*)(S + (size_t)bz * SEQ * SEQ), SEQ,
                     nullptr, DIMN, scale,
                     (mh * 8 + mm) * 128, nn * 256);
}

// PV: 256 blocks, 128x256, K=2048.
__global__ __launch_bounds__(512, 2)
void gemm_pv(const short* __restrict__ P, const short* __restrict__ vt,
             float* __restrict__ O)
{
    __shared__ alignas(16) char smem[G_LDSZ];
    const int b   = blockIdx.x;
    const int xcd = b & 7;
    const int i   = b >> 3;          // 0..31
    const int bz  = xcd >> 1;
    const int mh  = xcd & 1;
    const int mm  = i >> 2;          // 0..7
    const int nn  = i & 3;           // 0..3
    gemm128<false, 0>(smem, P  + (size_t)bz * SEQ * SEQ,  SEQ,
                      vt + (size_t)bz * DIMN * SEQ, SEQ,
                      (void*)(O + (size_t)bz * SEQ * DIMN), DIMN,
                      nullptr, SEQ, 1.f,
                      (mh * 8 + mm) * 128, nn * 256);
}

// ---------------------------------------------------------------------------
// cvt7: fp32->bf16 casts (z 0..5) + effective-bias computation (z==6).
// ---------------------------------------------------------------------------
__global__ __launch_bounds__(256)
void cvt7(const float* __restrict__ w0, short* __restrict__ ow0,
          const float* __restrict__ w1, short* __restrict__ ow1,
          const float* __restrict__ w2, short* __restrict__ ow2,
          const float* __restrict__ x0, short* __restrict__ ox0,
          const float* __restrict__ x1, short* __restrict__ ox1,
          const float* __restrict__ x2, short* __restrict__ ox2,
          const float* __restrict__ bq, const float* __restrict__ bk,
          const float* __restrict__ bv, const float* __restrict__ ctx,
          float* __restrict__ oq, float* __restrict__ ok, float* __restrict__ ov,
          int n8w, int n8x)
{
    const int z = blockIdx.z;
    if (z == 6) {
        // effective biases: out[n] = b[n] + dot(ctx, W[n,:]) (ctx only q,k)
        const int bx = blockIdx.x;
        if (bx >= 768) return;
        const int z2 = bx >> 8;              // 0..2
        const float* W = (z2 == 0) ? w0 : (z2 == 1) ? w1 : w2;
        const float* bb = (z2 == 0) ? bq : (z2 == 1) ? bk : bv;
        float*       o  = (z2 == 0) ? oq : (z2 == 1) ? ok : ov;
        const int n    = (bx & 255) * 4 + (threadIdx.x >> 6);
        const int lane = threadIdx.x & 63;
        float s = 0.f;
        if (z2 < 2) {
            const float* row = W + (size_t)n * DIMN;
            for (int kk = lane * 4; kk < DIMN; kk += 256) {
                const float4 x = *(const float4*)(row + kk);
                const float4 c = *(const float4*)(ctx + kk);
                s += x.x * c.x + x.y * c.y + x.z * c.z + x.w * c.w;
            }
            #pragma unroll
            for (int off = 32; off > 0; off >>= 1) s += __shfl_xor(s, off);
        }
        if (lane == 0) o[n] = bb[n] + s;
        return;
    }
    const float* in; short* out; int n8;
    switch (z) {
        case 0: in = w0; out = ow0; n8 = n8w; break;
        case 1: in = w1; out = ow1; n8 = n8w; break;
        case 2: in = w2; out = ow2; n8 = n8w; break;
        case 3: in = x0; out = ox0; n8 = n8x; break;
        case 4: in = x1; out = ox1; n8 = n8x; break;
        default: in = x2; out = ox2; n8 = n8x; break;
    }
    const int i = blockIdx.x * 256 + threadIdx.x;
    if (i >= n8) return;
    const float4 a0 = ((const float4*)in)[(size_t)i * 2];
    const float4 a1 = ((const float4*)in)[(size_t)i * 2 + 1];
    const float v[8] = {a0.x, a0.y, a0.z, a0.w, a1.x, a1.y, a1.z, a1.w};
    bf16x8 o;
    #pragma unroll
    for (int j = 0; j < 8; ++j) o[j] = f2bf(v[j]);
    *(bf16x8*)(out + (size_t)i * 8) = o;
}

// ---------------------------------------------------------------------------
// Row softmax, in place on bf16 [M1 rows][SEQ]. XCD-aligned with scores'
// writer (batch bz lives on XCDs {2bz, 2bz+1}) so reads hit that L2.
// ---------------------------------------------------------------------------
__global__ __launch_bounds__(256)
void softmax_kernel(short* __restrict__ P)
{
    const int bid = blockIdx.x;
    const int xcd = bid & 7;
    const int i   = bid >> 3;            // 0..1023
    const int row = (xcd >> 1) * SEQ + (xcd & 1) * 1024 + i;
    short* p = P + (size_t)row * SEQ;
    const int t    = threadIdx.x;
    const int lane = t & 63;
    const int wave = t >> 6;
    __shared__ float red[8];

    bf16x8 raw = *(const bf16x8*)(p + t * 8);
    float v[8];
    float mx = -1e30f;
    #pragma unroll
    for (int j = 0; j < 8; ++j) { v[j] = bf2f(raw[j]); mx = fmaxf(mx, v[j]); }
    #pragma unroll
    for (int off = 32; off > 0; off >>= 1) mx = fmaxf(mx, __shfl_xor(mx, off));
    if (lane == 0) red[wave] = mx;
    __syncthreads();
    mx = fmaxf(fmaxf(red[0], red[1]), fmaxf(red[2], red[3]));

    float e[8], s = 0.f;
    #pragma unroll
    for (int j = 0; j < 8; ++j) { e[j] = __expf(v[j] - mx); s += e[j]; }
    #pragma unroll
    for (int off = 32; off > 0; off >>= 1) s += __shfl_xor(s, off);
    if (lane == 0) red[4 + wave] = s;
    __syncthreads();
    s = red[4] + red[5] + red[6] + red[7];
    const float inv = 1.f / s;

    bf16x8 o;
    #pragma unroll
    for (int j = 0; j < 8; ++j) o[j] = f2bf(e[j] * inv);
    *(bf16x8*)(p + t * 8) = o;
}

// ---------------------------------------------------------------------------
extern "C" void kernel_launch(void* const* d_in, const int* in_sizes, int n_in,
                              void* d_out, int out_size, void* d_ws, size_t ws_size,
                              hipStream_t stream)
{
    const float* query = (const float*)d_in[0];
    const float* key_  = (const float*)d_in[1];
    const float* value = (const float*)d_in[2];
    const float* ctx   = (const float*)d_in[3];
    const float* Wq    = (const float*)d_in[4];
    const float* bq    = (const float*)d_in[5];
    const float* Wk    = (const float*)d_in[6];
    const float* bk    = (const float*)d_in[7];
    const float* Wv    = (const float*)d_in[8];
    const float* bv    = (const float*)d_in[9];

    // Memory plan (ws 80MB + d_out 32MB as scratch):
    //   ws:    xq [0,16) xk [16,32)   -> dead after proj -> S_b [0,32)
    //          q_b [32,48) k_b [48,64) v_t [64,80)
    //   d_out: xv [0,16)  W3 [16,22) + biases @22MB  -> all dead after proj
    //          -> final output (written only by gemm_pv at the end)
    char* ws = (char*)d_ws;
    char* od = (char*)d_out;
    const size_t MB = 1ull << 20;
    short* xq   = (short*)(ws);
    short* xk   = (short*)(ws + 16 * MB);
    short* q_b  = (short*)(ws + 32 * MB);
    short* k_b  = (short*)(ws + 48 * MB);
    short* v_t  = (short*)(ws + 64 * MB);
    short* S_b  = (short*)(ws);
    short* xv   = (short*)(od);
    short* Wq_b = (short*)(od + 16 * MB);
    short* Wk_b = (short*)(od + 18 * MB);
    short* Wv_b = (short*)(od + 20 * MB);
    float* bq_e = (float*)(od + 22 * MB);
    float* bk_e = (float*)(od + 22 * MB + 4096);
    float* bv_e = (float*)(od + 22 * MB + 8192);

    dim3 blk(256);
    dim3 blk512(512);
    const int W8 = DIMN * DIMN / 8;  // 131072
    const int X8 = M1 * DIMN / 8;    // 1048576

    cvt7<<<dim3(X8 / 256, 1, 7), blk, 0, stream>>>(
        Wq, Wq_b, Wk, Wk_b, Wv, Wv_b,
        query, xq, key_, xk, value, xv,
        bq, bk, bv, ctx, bq_e, bk_e, bv_e,
        W8, X8);

    proj_qkv<<<dim3(768), blk512, 0, stream>>>(xq, xk, xv, Wq_b, Wk_b, Wv_b,
                                               bq_e, bk_e, bv_e, q_b, k_b, v_t);

    const float scale = 1.0f / 32.0f; // DIMN^-0.5
    gemm_scores<<<dim3(512), blk512, 0, stream>>>(q_b, k_b, S_b, scale);

    softmax_kernel<<<dim3(M1), blk, 0, stream>>>(S_b);

    gemm_pv<<<dim3(256), blk512, 0, stream>>>(S_b, v_t, (float*)d_out);
}